// Round 4
// baseline (788.310 us; speedup 1.0000x reference)
//
#include <hip/hip_runtime.h>
#include <hip/hip_bf16.h>
#include <math.h>

#define NNODES 50000
#define NEDGES 800000
#define HD     256   // HEADS*DHEAD
#define CW     384   // comb width: q(256) | qwe(64) | skip(64)
#define NTOT   896   // Wc rows: q(256)|qwe(64)|skip(64)|v(256)|k(256)
#define QS     0.18033688011112042f   // 0.125 * log2(e): fold softmax scale into exp2

typedef __hip_bfloat16 bf16;
typedef unsigned short u16;
typedef unsigned char  u8;
typedef unsigned int   u32;
typedef unsigned long long u64;
typedef __attribute__((ext_vector_type(8))) short bf16x8;
typedef __attribute__((ext_vector_type(4))) float f32x4;
typedef __attribute__((ext_vector_type(2))) float f32x2;

__device__ __forceinline__ float lo16f(u32 u) { return __uint_as_float(u << 16); }
__device__ __forceinline__ float hi16f(u32 u) { return __uint_as_float(u & 0xFFFF0000u); }
__device__ __forceinline__ short f2s(float v) { __hip_bfloat16 h = __float2bfloat16(v); return *(short*)&h; }

// VALU cross-lane add within 16-lane groups
template<int CTRL>
__device__ __forceinline__ float dppadd(float x) {
    int t = __builtin_amdgcn_update_dpp(0, __float_as_int(x), CTRL, 0xF, 0xF, true);
    return x + __int_as_float(t);
}

// ---------------- CSR build ----------------
__global__ void hist_kernel(const int* __restrict__ dst, int* __restrict__ deg, int E) {
    int e = blockIdx.x * 256 + threadIdx.x;
    if (e < E) atomicAdd(&deg[dst[e]], 1);
}

__global__ void scanA(const int* __restrict__ deg, int* __restrict__ locincl,
                      int* __restrict__ blocksum, int n) {
    int tid = threadIdx.x;
    int i = blockIdx.x * 256 + tid;
    int v = (i < n) ? deg[i] : 0;
    int lane = tid & 63, w = tid >> 6;
    int s = v;
    #pragma unroll
    for (int off = 1; off < 64; off <<= 1) {
        int t = __shfl_up(s, off);
        if (lane >= off) s += t;
    }
    __shared__ int wsum[4];
    if (lane == 63) wsum[w] = s;
    __syncthreads();
    for (int ww = 0; ww < w; ww++) s += wsum[ww];
    if (i < n) locincl[i] = s;
    if (tid == 255) blocksum[blockIdx.x] = s;
}

__global__ void scanB(const int* __restrict__ blocksum, int* __restrict__ blockoff,
                      int nb, int* __restrict__ rowptr, int n) {
    int tid = threadIdx.x;
    int v = (tid < nb) ? blocksum[tid] : 0;
    int lane = tid & 63, w = tid >> 6;
    int s = v;
    #pragma unroll
    for (int off = 1; off < 64; off <<= 1) {
        int t = __shfl_up(s, off);
        if (lane >= off) s += t;
    }
    __shared__ int wsum[4];
    if (lane == 63) wsum[w] = s;
    __syncthreads();
    for (int ww = 0; ww < w; ww++) s += wsum[ww];
    if (tid < nb) blockoff[tid] = s - v;
    if (tid == 255) rowptr[n] = s;
}

__global__ void scanC(const int* __restrict__ deg, const int* __restrict__ locincl,
                      const int* __restrict__ blockoff,
                      int* __restrict__ rowptr, int* __restrict__ cursor, int n) {
    int i = blockIdx.x * 256 + threadIdx.x;
    if (i < n) {
        int ex = locincl[i] - deg[i] + blockoff[blockIdx.x];
        rowptr[i] = ex;
        cursor[i] = ex;
    }
}

__global__ void scatter_kernel(const int* __restrict__ src, const int* __restrict__ dst,
                               int* __restrict__ cursor, int2* __restrict__ csr2, int E) {
    int e = blockIdx.x * 256 + threadIdx.x;
    if (e < E) {
        int d = dst[e];
        int p = atomicAdd(&cursor[d], 1);
        csr2[p] = make_int2(src[e], e);
    }
}

// ---- pack: 896 rows n-major bf16 [NTOT][K] + fp32 bias ----
// rows: q(0..255)*QS | qwe(256..319)*QS | skip(320..383) | v(384..639) | k(640..895)
__global__ void pack_all(const float* __restrict__ Wq, const float* __restrict__ bq,
                         const float* __restrict__ Wk, const float* __restrict__ bk,
                         const float* __restrict__ Wv, const float* __restrict__ bv,
                         const float* __restrict__ We,
                         const float* __restrict__ Ws, const float* __restrict__ bs,
                         bf16* __restrict__ Wc, float* __restrict__ b, int K) {
    int n = blockIdx.x, c = threadIdx.x;
    float v, bb;
    if (n < 256)      { v = Wq[(size_t)c * 256 + n] * QS;    bb = bq[n] * QS; }
    else if (n < 320) {
        int t = n - 256, h = t >> 4, j = t & 15;
        float s = 0.f, sb = 0.f;
        #pragma unroll 8
        for (int d = 0; d < 64; d++) {
            float wv = We[j * HD + h * 64 + d];
            s += Wq[(size_t)c * 256 + h * 64 + d] * wv;
            sb += bq[h * 64 + d] * wv;
        }
        v = s * QS; bb = sb * QS;
    }
    else if (n < 384) { v = Ws[(size_t)c * 64  + (n - 320)]; bb = bs[n - 320]; }
    else if (n < 640) { v = Wv[(size_t)c * 256 + (n - 384)]; bb = bv[n - 384]; }
    else              { v = Wk[(size_t)c * 256 + (n - 640)]; bb = bk[n - 640]; }
    Wc[(size_t)n * K + c] = __float2bfloat16(v);
    if (c == 0) b[n] = bb;
}

// ---------------- barrier-free MFMA GEMM -> comb[Nx384] | vbuf[Nx256] | k8[Nx256 fp8] ----------------
// A-frags in registers; B-fragments loaded DIRECTLY from global (Wc is 229 KB, L2-resident,
// shared by all blocks; each load inst covers 16 rows x 64 B contiguous = full lines).
// No LDS, no __syncthreads: waves pipeline freely. grid.y=2 splits the 14 chunks 7/7.
template<typename TA, int K>
__global__ void __launch_bounds__(256) gemm_fused(
    const TA* __restrict__ A, const bf16* __restrict__ Wc, const float* __restrict__ bias,
    bf16* __restrict__ comb, bf16* __restrict__ vbuf, u8* __restrict__ k8)
{
    constexpr int KS = K / 32;    // MFMA k-steps
    int tid = threadIdx.x, w = tid >> 6, lane = tid & 63;
    int cl = lane & 15, aq = lane >> 4;
    int m = blockIdx.x * 64 + w * 16 + cl;
    int rowc = (m < NNODES) ? m : (NNODES - 1);
    int cbeg = blockIdx.y * 7;    // chunks cbeg .. cbeg+6

    bf16x8 af[KS];
    if constexpr (sizeof(TA) == 4) {
        const float* ar = (const float*)A + (size_t)rowc * K;
        #pragma unroll
        for (int ks = 0; ks < KS; ks++) {
            const float4* ap = (const float4*)(ar + ks * 32 + aq * 8);
            float4 f0 = ap[0], f1 = ap[1];
            union { short s[8]; bf16x8 v; } t;
            t.s[0] = f2s(f0.x); t.s[1] = f2s(f0.y); t.s[2] = f2s(f0.z); t.s[3] = f2s(f0.w);
            t.s[4] = f2s(f1.x); t.s[5] = f2s(f1.y); t.s[6] = f2s(f1.z); t.s[7] = f2s(f1.w);
            af[ks] = t.v;
        }
    } else {
        const u16* ar = (const u16*)A + (size_t)rowc * K;
        #pragma unroll
        for (int ks = 0; ks < KS; ks++) af[ks] = *(const bf16x8*)(ar + ks * 32 + aq * 8);
    }

    for (int ci = 0; ci < 7; ci++) {
        int chunk = cbeg + ci;
        const u16* wbase = (const u16*)Wc + (size_t)chunk * 64 * K + (size_t)cl * K + aq * 8;
        f32x4 acc[4] = {};
        #pragma unroll
        for (int t = 0; t < 4; t++) {
            #pragma unroll
            for (int ks = 0; ks < KS; ks++) {
                bf16x8 bfr = *(const bf16x8*)(wbase + (size_t)t * 16 * K + ks * 32);
                acc[t] = __builtin_amdgcn_mfma_f32_16x16x32_bf16(bfr, af[ks], acc[t], 0, 0, 0);
            }
        }
        if (m >= NNODES) continue;
        if (chunk < 10) {
            u16* dst;
            if (chunk < 6) dst = (u16*)comb + (size_t)m * CW + chunk * 64;
            else           dst = (u16*)vbuf + (size_t)m * 256 + (chunk - 6) * 64;
            #pragma unroll
            for (int t = 0; t < 4; t++) {
                float4 bv = *(const float4*)&bias[chunk * 64 + t * 16 + aq * 4];
                u32 lo = (u32)(u16)f2s(acc[t][0] + bv.x) | ((u32)(u16)f2s(acc[t][1] + bv.y) << 16);
                u32 hi = (u32)(u16)f2s(acc[t][2] + bv.z) | ((u32)(u16)f2s(acc[t][3] + bv.w) << 16);
                *(uint2*)(dst + t * 16 + aq * 4) = make_uint2(lo, hi);
            }
        } else {
            u8* dst = k8 + (size_t)m * 256 + (chunk - 10) * 64;
            #pragma unroll
            for (int t = 0; t < 4; t++) {
                float4 bv = *(const float4*)&bias[chunk * 64 + t * 16 + aq * 4];
                u32 pk = __builtin_amdgcn_cvt_pk_fp8_f32(acc[t][0] + bv.x, acc[t][1] + bv.y, 0, false);
                pk = __builtin_amdgcn_cvt_pk_fp8_f32(acc[t][2] + bv.z, acc[t][3] + bv.w, pk, true);
                *(u32*)(dst + t * 16 + aq * 4) = pk;
            }
        }
    }
}

// ---------------- fused edge-logit + node aggregation + epilogue ----------------
// One wave per node. Wave-uniform edge values forced into SGPRs via readfirstlane ->
// all three gathers become saddr-form loads (SGPR base + const voffset, zero VALU addressing).
__global__ void __launch_bounds__(256) node_fused(
    const int* __restrict__ rowptr, const int2* __restrict__ csr2,
    const float* __restrict__ eattr, const u16* __restrict__ comb,
    const u16* __restrict__ vbuf, const u8* __restrict__ k8,
    const float* __restrict__ We, const float* __restrict__ lng, const float* __restrict__ lnb,
    bf16* __restrict__ outB, float* __restrict__ outF)
{
    int tid = threadIdx.x, w = tid >> 6, lane = tid & 63;
    int n = blockIdx.x * 4 + w;                  // 12500 * 4 == NNODES exactly
    int hg = lane >> 4, j16 = lane & 15, coff = 4 * lane;
    __shared__ float sAV[4][256];
    __shared__ float sAE[4][64];

    const u16* crow = comb + (size_t)n * CW;
    uint2 qv = *(const uint2*)(crow + coff);     // q channels coff..coff+3 (pre-scaled by QS)
    float qf0 = lo16f(qv.x), qf1 = hi16f(qv.x), qf2 = lo16f(qv.y), qf3 = hi16f(qv.y);
    float qwe_r = __uint_as_float((u32)crow[256 + lane] << 16);   // qwe (pre-scaled)

    int e0 = __builtin_amdgcn_readfirstlane(rowptr[n]);
    int e1 = __builtin_amdgcn_readfirstlane(rowptr[n + 1]);

    float ss = 0.f, av0 = 0.f, av1 = 0.f, av2 = 0.f, av3 = 0.f, ae = 0.f;
    u32 vo = (u32)coff * 2u;
    u32 eo = (u32)j16 * 4u;

    auto EDGE = [&](int2 me) {
        u32 s   = (u32)__builtin_amdgcn_readfirstlane(me.x);   // wave-uniform -> SGPR
        u32 eid = (u32)__builtin_amdgcn_readfirstlane(me.y);
        const char* kp = (const char*)k8    + ((size_t)s << 8);
        const char* vp = (const char*)vbuf  + ((size_t)s << 9);
        const char* ep = (const char*)eattr + ((size_t)eid << 6);
        u32   kw = *(const u32*)  (kp + coff);
        uint2 vw = *(const uint2*)(vp + vo);
        float ea = *(const float*)(ep + eo);
        f32x2 k01 = __builtin_amdgcn_cvt_pk_f32_fp8(kw, false);
        f32x2 k23 = __builtin_amdgcn_cvt_pk_f32_fp8(kw, true);
        float part = qf0 * k01[0] + qf1 * k01[1] + qf2 * k23[0] + qf3 * k23[1] + qwe_r * ea;
        part = dppadd<0xB1>(part);    // xor 1
        part = dppadd<0x4E>(part);    // xor 2
        part = dppadd<0x141>(part);   // xor 4 (row_half_mirror)
        part = dppadd<0x140>(part);   // xor 8 (row_mirror)
        float alpha = __builtin_amdgcn_exp2f(part);   // scale folded into q at pack time
        ss += alpha;
        ae += alpha * ea;
        av0 += alpha * lo16f(vw.x); av1 += alpha * hi16f(vw.x);
        av2 += alpha * lo16f(vw.y); av3 += alpha * hi16f(vw.y);
    };

    int i = e0;
    int2 c0 = make_int2(0, 0), c1 = c0, c2 = c0, c3 = c0;
    if (i + 3 < e1) { c0 = csr2[i]; c1 = csr2[i + 1]; c2 = csr2[i + 2]; c3 = csr2[i + 3]; }
    for (; i + 7 < e1; i += 4) {
        int2 p0 = csr2[i + 4], p1 = csr2[i + 5], p2 = csr2[i + 6], p3 = csr2[i + 7];
        EDGE(c0); EDGE(c1); EDGE(c2); EDGE(c3);
        c0 = p0; c1 = p1; c2 = p2; c3 = p3;
    }
    if (i + 3 < e1) { EDGE(c0); EDGE(c1); EDGE(c2); EDGE(c3); i += 4; }
    for (; i < e1; ++i) { int2 cc = csr2[i]; EDGE(cc); }

    // epilogue (all waves active; same-wave LDS transpose, no barrier)
    float inv = (ss > 0.f) ? 1.f / ss : 0.f;     // uniform within each 16-lane head group
    *(float4*)&sAV[w][coff] = make_float4(av0 * inv, av1 * inv, av2 * inv, av3 * inv);
    sAE[w][lane] = ae * inv;

    int d = lane;
    float val = 0.f;
    #pragma unroll
    for (int h = 0; h < 4; h++) {
        float xv = sAV[w][h * 64 + d];
        #pragma unroll
        for (int j = 0; j < 16; j++) xv += sAE[w][h * 16 + j] * We[j * HD + h * 64 + d];
        val += xv;
    }
    val = val * 0.25f + __uint_as_float((u32)crow[320 + d] << 16);   // head mean + skip

    float m = val;
    #pragma unroll
    for (int off = 1; off < 64; off <<= 1) m += __shfl_xor(m, off);
    m *= (1.f / 64.f);
    float diff = val - m;
    float vr = diff * diff;
    #pragma unroll
    for (int off = 1; off < 64; off <<= 1) vr += __shfl_xor(vr, off);
    vr *= (1.f / 64.f);
    float y = diff * rsqrtf(vr + 1e-5f) * lng[d] + lnb[d];
    float ge = 0.5f * y * (1.f + erff(y * 0.70710678118654752f));    // exact GELU
    if (outF) outF[(size_t)n * 64 + d] = ge;
    else      outB[(size_t)n * 64 + d] = __float2bfloat16(ge);
}

extern "C" void kernel_launch(void* const* d_in, const int* in_sizes, int n_in,
                              void* d_out, int out_size, void* d_ws, size_t ws_size,
                              hipStream_t stream)
{
    const float* x     = (const float*)d_in[0];
    const int*   eidx  = (const int*)d_in[1];
    const float* eattr = (const float*)d_in[2];
    struct P { const float *Wq,*bq,*Wk,*bk,*Wv,*bv,*We,*Ws,*bs; };
    P p[3];
    for (int l = 0; l < 3; l++) {
        int base = 3 + l * 9;
        p[l].Wq = (const float*)d_in[base + 0]; p[l].bq = (const float*)d_in[base + 1];
        p[l].Wk = (const float*)d_in[base + 2]; p[l].bk = (const float*)d_in[base + 3];
        p[l].Wv = (const float*)d_in[base + 4]; p[l].bv = (const float*)d_in[base + 5];
        p[l].We = (const float*)d_in[base + 6];
        p[l].Ws = (const float*)d_in[base + 7]; p[l].bs = (const float*)d_in[base + 8];
    }
    const float* lng = (const float*)d_in[30];
    const float* lnb = (const float*)d_in[31];

    // Workspace: ~91 MB
    char* ws = (char*)d_ws;
    size_t off = 0;
    auto alloc = [&](size_t bytes) { void* pp = ws + off; off += (bytes + 255) & ~(size_t)255; return pp; };
    int*   rowptr   = (int*)  alloc((NNODES + 1) * 4);
    int*   cursor   = (int*)  alloc(NNODES * 4);
    int*   deg      = (int*)  alloc(NNODES * 4);
    int*   blocksum = (int*)  alloc(256 * 4);
    int*   blockoff = (int*)  alloc(256 * 4);
    int2*  csr2     = (int2*) alloc((size_t)NEDGES * 8);        // 6.4 MB
    bf16*  hbuf     = (bf16*) alloc((size_t)NNODES * 64 * 2);   // 6.4 MB
    bf16*  comb     = (bf16*) alloc((size_t)NNODES * CW * 2);   // 38.4 MB: q|qwe|skip
    bf16*  vbuf     = (bf16*) alloc((size_t)NNODES * 256 * 2);  // 25.6 MB: v (512-B rows)
    u8*    k8       = (u8*)   alloc((size_t)NNODES * 256);      // 12.8 MB fp8 k
    bf16*  Wc       = (bf16*) alloc((size_t)NTOT * 128 * 2);    // 229 KB
    float* b896     = (float*)alloc(NTOT * 4);
    (void)ws_size;

    const int* srcArr = eidx;           // edge_index[0]
    const int* dstArr = eidx + NEDGES;  // edge_index[1]

    // CSR build (multi-block scan)
    int NB = (NNODES + 255) / 256;
    (void)hipMemsetAsync(deg, 0, NNODES * 4, stream);
    hist_kernel<<<(NEDGES + 255) / 256, 256, 0, stream>>>(dstArr, deg, NEDGES);
    scanA<<<NB, 256, 0, stream>>>(deg, cursor, blocksum, NNODES);
    scanB<<<1, 256, 0, stream>>>(blocksum, blockoff, NB, rowptr, NNODES);
    scanC<<<NB, 256, 0, stream>>>(deg, cursor, blockoff, rowptr, cursor, NNODES);
    scatter_kernel<<<(NEDGES + 255) / 256, 256, 0, stream>>>(srcArr, dstArr, cursor, csr2, NEDGES);

    int gm = (NNODES + 63) / 64;   // 782
    int fins[3] = {128, 64, 64};

    const void* hin = x;
    for (int l = 0; l < 3; l++) {
        int FIN = fins[l];
        pack_all<<<NTOT, FIN, 0, stream>>>(p[l].Wq, p[l].bq, p[l].Wk, p[l].bk,
                                           p[l].Wv, p[l].bv, p[l].We, p[l].Ws, p[l].bs,
                                           Wc, b896, FIN);
        if (l == 0) gemm_fused<float, 128><<<dim3(gm, 2), 256, 0, stream>>>((const float*)hin, Wc, b896, comb, vbuf, k8);
        else        gemm_fused<bf16,  64><<<dim3(gm, 2), 256, 0, stream>>>((const bf16*)hin,  Wc, b896, comb, vbuf, k8);
        node_fused<<<NNODES / 4, 256, 0, stream>>>(rowptr, csr2, eattr, (const u16*)comb,
            (const u16*)vbuf, k8, p[l].We, lng, lnb,
            (l == 2) ? nullptr : hbuf, (l == 2) ? (float*)d_out : nullptr);
        hin = hbuf;
    }
}

// Round 5
// 689.914 us; speedup vs baseline: 1.1426x; 1.1426x over previous
//
#include <hip/hip_runtime.h>
#include <hip/hip_bf16.h>
#include <math.h>

#define NNODES 50000
#define NEDGES 800000
#define HD     256   // HEADS*DHEAD
#define CW     384   // comb width: q(256) | qwe(64) | skip(64)
#define NTOT   896   // Wc rows: q(256)|qwe(64)|skip(64)|v(256)|k(256)
#define QS     0.18033688011112042f   // 0.125 * log2(e): fold softmax scale into exp2

typedef __hip_bfloat16 bf16;
typedef unsigned short u16;
typedef unsigned char  u8;
typedef unsigned int   u32;
typedef unsigned long long u64;
typedef __attribute__((ext_vector_type(8))) short bf16x8;
typedef __attribute__((ext_vector_type(4))) float f32x4;
typedef __attribute__((ext_vector_type(2))) float f32x2;

__device__ __forceinline__ float lo16f(u32 u) { return __uint_as_float(u << 16); }
__device__ __forceinline__ float hi16f(u32 u) { return __uint_as_float(u & 0xFFFF0000u); }
__device__ __forceinline__ short f2s(float v) { __hip_bfloat16 h = __float2bfloat16(v); return *(short*)&h; }

// VALU cross-lane add within 16-lane groups
template<int CTRL>
__device__ __forceinline__ float dppadd(float x) {
    int t = __builtin_amdgcn_update_dpp(0, __float_as_int(x), CTRL, 0xF, 0xF, true);
    return x + __int_as_float(t);
}

// ---------------- CSR build ----------------
__global__ void hist_kernel(const int* __restrict__ dst, int* __restrict__ deg, int E) {
    int e = blockIdx.x * 256 + threadIdx.x;
    if (e < E) atomicAdd(&deg[dst[e]], 1);
}

__global__ void scanA(const int* __restrict__ deg, int* __restrict__ locincl,
                      int* __restrict__ blocksum, int n) {
    int tid = threadIdx.x;
    int i = blockIdx.x * 256 + tid;
    int v = (i < n) ? deg[i] : 0;
    int lane = tid & 63, w = tid >> 6;
    int s = v;
    #pragma unroll
    for (int off = 1; off < 64; off <<= 1) {
        int t = __shfl_up(s, off);
        if (lane >= off) s += t;
    }
    __shared__ int wsum[4];
    if (lane == 63) wsum[w] = s;
    __syncthreads();
    for (int ww = 0; ww < w; ww++) s += wsum[ww];
    if (i < n) locincl[i] = s;
    if (tid == 255) blocksum[blockIdx.x] = s;
}

__global__ void scanB(const int* __restrict__ blocksum, int* __restrict__ blockoff,
                      int nb, int* __restrict__ rowptr, int n) {
    int tid = threadIdx.x;
    int v = (tid < nb) ? blocksum[tid] : 0;
    int lane = tid & 63, w = tid >> 6;
    int s = v;
    #pragma unroll
    for (int off = 1; off < 64; off <<= 1) {
        int t = __shfl_up(s, off);
        if (lane >= off) s += t;
    }
    __shared__ int wsum[4];
    if (lane == 63) wsum[w] = s;
    __syncthreads();
    for (int ww = 0; ww < w; ww++) s += wsum[ww];
    if (tid < nb) blockoff[tid] = s - v;
    if (tid == 255) rowptr[n] = s;
}

__global__ void scanC(const int* __restrict__ deg, const int* __restrict__ locincl,
                      const int* __restrict__ blockoff,
                      int* __restrict__ rowptr, int* __restrict__ cursor, int n) {
    int i = blockIdx.x * 256 + threadIdx.x;
    if (i < n) {
        int ex = locincl[i] - deg[i] + blockoff[blockIdx.x];
        rowptr[i] = ex;
        cursor[i] = ex;
    }
}

__global__ void scatter_kernel(const int* __restrict__ src, const int* __restrict__ dst,
                               int* __restrict__ cursor, int2* __restrict__ csr2, int E) {
    int e = blockIdx.x * 256 + threadIdx.x;
    if (e < E) {
        int d = dst[e];
        int p = atomicAdd(&cursor[d], 1);
        csr2[p] = make_int2(src[e], e);
    }
}

// ---- pack: 896 rows n-major bf16 [NTOT][K] + fp32 bias ----
// rows: q(0..255)*QS | qwe(256..319)*QS | skip(320..383) | v(384..639) | k(640..895)
__global__ void pack_all(const float* __restrict__ Wq, const float* __restrict__ bq,
                         const float* __restrict__ Wk, const float* __restrict__ bk,
                         const float* __restrict__ Wv, const float* __restrict__ bv,
                         const float* __restrict__ We,
                         const float* __restrict__ Ws, const float* __restrict__ bs,
                         bf16* __restrict__ Wc, float* __restrict__ b, int K) {
    int n = blockIdx.x, c = threadIdx.x;
    float v, bb;
    if (n < 256)      { v = Wq[(size_t)c * 256 + n] * QS;    bb = bq[n] * QS; }
    else if (n < 320) {
        int t = n - 256, h = t >> 4, j = t & 15;
        float s = 0.f, sb = 0.f;
        #pragma unroll 8
        for (int d = 0; d < 64; d++) {
            float wv = We[j * HD + h * 64 + d];
            s += Wq[(size_t)c * 256 + h * 64 + d] * wv;
            sb += bq[h * 64 + d] * wv;
        }
        v = s * QS; bb = sb * QS;
    }
    else if (n < 384) { v = Ws[(size_t)c * 64  + (n - 320)]; bb = bs[n - 320]; }
    else if (n < 640) { v = Wv[(size_t)c * 256 + (n - 384)]; bb = bv[n - 384]; }
    else              { v = Wk[(size_t)c * 256 + (n - 640)]; bb = bk[n - 640]; }
    Wc[(size_t)n * K + c] = __float2bfloat16(v);
    if (c == 0) b[n] = bb;
}

// ---------------- MFMA GEMM, B-slice resident in LDS ----------------
// Grid (7, 196): blockIdx.x = slice of 2 chunks (B-slice staged to LDS ONCE, 1 barrier),
// blockIdx.y = m-block of 256 rows (4 iters x 64). Main loop: zero barriers, zero global
// B-loads; A-fragments register double-buffered. Slice is the fast dispatch dim so the
// 7 blocks sharing an A-range run together (A L2-hot).
template<typename TA, int K>
__global__ void __launch_bounds__(256) gemm_lds(
    const TA* __restrict__ A, const bf16* __restrict__ Wc, const float* __restrict__ bias,
    bf16* __restrict__ comb, bf16* __restrict__ vbuf, u8* __restrict__ k8)
{
    constexpr int KS  = K / 32;   // MFMA k-steps
    constexpr int CPR = K / 8;    // 16B granules per B row
    constexpr int ITERS = 4;
    __shared__ short Bl[128 * K];
    int tid = threadIdx.x, w = tid >> 6, lane = tid & 63;
    int cl = lane & 15, aq = lane >> 4;
    int c0 = blockIdx.x * 2;      // chunks c0, c0+1

    // stage B-slice (128 rows x K) once, XOR-swizzled granules
    #pragma unroll
    for (int p = 0; p < CPR / 2; p++) {
        int slot = tid + p * 256;
        int row = slot / CPR, j = slot % CPR;
        *(uint4*)&Bl[row * K + ((j ^ (row & 7)) << 3)] =
            *(const uint4*)((const u16*)Wc + (size_t)(c0 * 64 + row) * K + (j << 3));
    }
    __syncthreads();

    int mrow = blockIdx.y * (64 * ITERS) + w * 16 + cl;

    auto LOADA = [&](bf16x8* af, int m) {
        int rc = (m < NNODES) ? m : (NNODES - 1);
        if constexpr (sizeof(TA) == 4) {
            const float* ar = (const float*)A + (size_t)rc * K + aq * 8;
            #pragma unroll
            for (int ks = 0; ks < KS; ks++) {
                const float4* ap = (const float4*)(ar + ks * 32);
                float4 f0 = ap[0], f1 = ap[1];
                union { short s[8]; bf16x8 v; } t;
                t.s[0] = f2s(f0.x); t.s[1] = f2s(f0.y); t.s[2] = f2s(f0.z); t.s[3] = f2s(f0.w);
                t.s[4] = f2s(f1.x); t.s[5] = f2s(f1.y); t.s[6] = f2s(f1.z); t.s[7] = f2s(f1.w);
                af[ks] = t.v;
            }
        } else {
            const u16* ar = (const u16*)A + (size_t)rc * K + aq * 8;
            #pragma unroll
            for (int ks = 0; ks < KS; ks++) af[ks] = *(const bf16x8*)(ar + ks * 32);
        }
    };

    bf16x8 cur[KS], nxt[KS];
    LOADA(cur, mrow);
    #pragma unroll
    for (int it = 0; it < ITERS; it++) {
        int m = mrow + it * 64;
        if (it + 1 < ITERS) LOADA(nxt, m + 64);   // prefetch next A-tile
        #pragma unroll
        for (int c = 0; c < 2; c++) {
            int chunk = c0 + c;
            f32x4 acc[4] = {};
            #pragma unroll
            for (int t = 0; t < 4; t++) {
                #pragma unroll
                for (int ks = 0; ks < KS; ks++) {
                    bf16x8 bfr = *(const bf16x8*)&Bl[(c * 64 + t * 16 + cl) * K +
                                                     (((ks * 4 + aq) ^ (cl & 7)) << 3)];
                    acc[t] = __builtin_amdgcn_mfma_f32_16x16x32_bf16(bfr, cur[ks], acc[t], 0, 0, 0);
                }
            }
            if (m < NNODES) {
                if (chunk < 10) {
                    u16* dst = (chunk < 6) ? (u16*)comb + (size_t)m * CW + chunk * 64
                                           : (u16*)vbuf + (size_t)m * 256 + (chunk - 6) * 64;
                    #pragma unroll
                    for (int t = 0; t < 4; t++) {
                        float4 bv = *(const float4*)&bias[chunk * 64 + t * 16 + aq * 4];
                        u32 lo = (u32)(u16)f2s(acc[t][0] + bv.x) | ((u32)(u16)f2s(acc[t][1] + bv.y) << 16);
                        u32 hi = (u32)(u16)f2s(acc[t][2] + bv.z) | ((u32)(u16)f2s(acc[t][3] + bv.w) << 16);
                        *(uint2*)(dst + t * 16 + aq * 4) = make_uint2(lo, hi);
                    }
                } else {
                    u8* dst = k8 + (size_t)m * 256 + (chunk - 10) * 64;
                    #pragma unroll
                    for (int t = 0; t < 4; t++) {
                        float4 bv = *(const float4*)&bias[chunk * 64 + t * 16 + aq * 4];
                        u32 pk = __builtin_amdgcn_cvt_pk_fp8_f32(acc[t][0] + bv.x, acc[t][1] + bv.y, 0, false);
                        pk = __builtin_amdgcn_cvt_pk_fp8_f32(acc[t][2] + bv.z, acc[t][3] + bv.w, pk, true);
                        *(u32*)(dst + t * 16 + aq * 4) = pk;
                    }
                }
            }
        }
        #pragma unroll
        for (int ks = 0; ks < KS; ks++) cur[ks] = nxt[ks];
    }
}

// ---------------- fused edge-logit + node aggregation + epilogue ----------------
// One wave per node. Wave-uniform edge values forced into SGPRs via readfirstlane ->
// all three gathers become saddr-form loads (SGPR base + const voffset, zero VALU addressing).
__global__ void __launch_bounds__(256) node_fused(
    const int* __restrict__ rowptr, const int2* __restrict__ csr2,
    const float* __restrict__ eattr, const u16* __restrict__ comb,
    const u16* __restrict__ vbuf, const u8* __restrict__ k8,
    const float* __restrict__ We, const float* __restrict__ lng, const float* __restrict__ lnb,
    bf16* __restrict__ outB, float* __restrict__ outF)
{
    int tid = threadIdx.x, w = tid >> 6, lane = tid & 63;
    int n = blockIdx.x * 4 + w;                  // 12500 * 4 == NNODES exactly
    int hg = lane >> 4, j16 = lane & 15, coff = 4 * lane;
    __shared__ float sAV[4][256];
    __shared__ float sAE[4][64];

    const u16* crow = comb + (size_t)n * CW;
    uint2 qv = *(const uint2*)(crow + coff);     // q channels coff..coff+3 (pre-scaled by QS)
    float qf0 = lo16f(qv.x), qf1 = hi16f(qv.x), qf2 = lo16f(qv.y), qf3 = hi16f(qv.y);
    float qwe_r = __uint_as_float((u32)crow[256 + lane] << 16);   // qwe (pre-scaled)

    int e0 = __builtin_amdgcn_readfirstlane(rowptr[n]);
    int e1 = __builtin_amdgcn_readfirstlane(rowptr[n + 1]);

    float ss = 0.f, av0 = 0.f, av1 = 0.f, av2 = 0.f, av3 = 0.f, ae = 0.f;
    u32 vo = (u32)coff * 2u;
    u32 eo = (u32)j16 * 4u;

    auto EDGE = [&](int2 me) {
        u32 s   = (u32)__builtin_amdgcn_readfirstlane(me.x);   // wave-uniform -> SGPR
        u32 eid = (u32)__builtin_amdgcn_readfirstlane(me.y);
        const char* kp = (const char*)k8    + ((size_t)s << 8);
        const char* vp = (const char*)vbuf  + ((size_t)s << 9);
        const char* ep = (const char*)eattr + ((size_t)eid << 6);
        u32   kw = *(const u32*)  (kp + coff);
        uint2 vw = *(const uint2*)(vp + vo);
        float ea = *(const float*)(ep + eo);
        f32x2 k01 = __builtin_amdgcn_cvt_pk_f32_fp8(kw, false);
        f32x2 k23 = __builtin_amdgcn_cvt_pk_f32_fp8(kw, true);
        float part = qf0 * k01[0] + qf1 * k01[1] + qf2 * k23[0] + qf3 * k23[1] + qwe_r * ea;
        part = dppadd<0xB1>(part);    // xor 1
        part = dppadd<0x4E>(part);    // xor 2
        part = dppadd<0x141>(part);   // xor 4 (row_half_mirror)
        part = dppadd<0x140>(part);   // xor 8 (row_mirror)
        float alpha = __builtin_amdgcn_exp2f(part);   // scale folded into q at pack time
        ss += alpha;
        ae += alpha * ea;
        av0 += alpha * lo16f(vw.x); av1 += alpha * hi16f(vw.x);
        av2 += alpha * lo16f(vw.y); av3 += alpha * hi16f(vw.y);
    };

    int i = e0;
    int2 c0 = make_int2(0, 0), c1 = c0, c2 = c0, c3 = c0;
    if (i + 3 < e1) { c0 = csr2[i]; c1 = csr2[i + 1]; c2 = csr2[i + 2]; c3 = csr2[i + 3]; }
    for (; i + 7 < e1; i += 4) {
        int2 p0 = csr2[i + 4], p1 = csr2[i + 5], p2 = csr2[i + 6], p3 = csr2[i + 7];
        EDGE(c0); EDGE(c1); EDGE(c2); EDGE(c3);
        c0 = p0; c1 = p1; c2 = p2; c3 = p3;
    }
    if (i + 3 < e1) { EDGE(c0); EDGE(c1); EDGE(c2); EDGE(c3); i += 4; }
    for (; i < e1; ++i) { int2 cc = csr2[i]; EDGE(cc); }

    // epilogue (all waves active; same-wave LDS transpose, no barrier)
    float inv = (ss > 0.f) ? 1.f / ss : 0.f;     // uniform within each 16-lane head group
    *(float4*)&sAV[w][coff] = make_float4(av0 * inv, av1 * inv, av2 * inv, av3 * inv);
    sAE[w][lane] = ae * inv;

    int d = lane;
    float val = 0.f;
    #pragma unroll
    for (int h = 0; h < 4; h++) {
        float xv = sAV[w][h * 64 + d];
        #pragma unroll
        for (int j = 0; j < 16; j++) xv += sAE[w][h * 16 + j] * We[j * HD + h * 64 + d];
        val += xv;
    }
    val = val * 0.25f + __uint_as_float((u32)crow[320 + d] << 16);   // head mean + skip

    float m = val;
    #pragma unroll
    for (int off = 1; off < 64; off <<= 1) m += __shfl_xor(m, off);
    m *= (1.f / 64.f);
    float diff = val - m;
    float vr = diff * diff;
    #pragma unroll
    for (int off = 1; off < 64; off <<= 1) vr += __shfl_xor(vr, off);
    vr *= (1.f / 64.f);
    float y = diff * rsqrtf(vr + 1e-5f) * lng[d] + lnb[d];
    float ge = 0.5f * y * (1.f + erff(y * 0.70710678118654752f));    // exact GELU
    if (outF) outF[(size_t)n * 64 + d] = ge;
    else      outB[(size_t)n * 64 + d] = __float2bfloat16(ge);
}

extern "C" void kernel_launch(void* const* d_in, const int* in_sizes, int n_in,
                              void* d_out, int out_size, void* d_ws, size_t ws_size,
                              hipStream_t stream)
{
    const float* x     = (const float*)d_in[0];
    const int*   eidx  = (const int*)d_in[1];
    const float* eattr = (const float*)d_in[2];
    struct P { const float *Wq,*bq,*Wk,*bk,*Wv,*bv,*We,*Ws,*bs; };
    P p[3];
    for (int l = 0; l < 3; l++) {
        int base = 3 + l * 9;
        p[l].Wq = (const float*)d_in[base + 0]; p[l].bq = (const float*)d_in[base + 1];
        p[l].Wk = (const float*)d_in[base + 2]; p[l].bk = (const float*)d_in[base + 3];
        p[l].Wv = (const float*)d_in[base + 4]; p[l].bv = (const float*)d_in[base + 5];
        p[l].We = (const float*)d_in[base + 6];
        p[l].Ws = (const float*)d_in[base + 7]; p[l].bs = (const float*)d_in[base + 8];
    }
    const float* lng = (const float*)d_in[30];
    const float* lnb = (const float*)d_in[31];

    // Workspace: ~91 MB
    char* ws = (char*)d_ws;
    size_t off = 0;
    auto alloc = [&](size_t bytes) { void* pp = ws + off; off += (bytes + 255) & ~(size_t)255; return pp; };
    int*   rowptr   = (int*)  alloc((NNODES + 1) * 4);
    int*   cursor   = (int*)  alloc(NNODES * 4);
    int*   deg      = (int*)  alloc(NNODES * 4);
    int*   blocksum = (int*)  alloc(256 * 4);
    int*   blockoff = (int*)  alloc(256 * 4);
    int2*  csr2     = (int2*) alloc((size_t)NEDGES * 8);        // 6.4 MB
    bf16*  hbuf     = (bf16*) alloc((size_t)NNODES * 64 * 2);   // 6.4 MB
    bf16*  comb     = (bf16*) alloc((size_t)NNODES * CW * 2);   // 38.4 MB: q|qwe|skip
    bf16*  vbuf     = (bf16*) alloc((size_t)NNODES * 256 * 2);  // 25.6 MB: v (512-B rows)
    u8*    k8       = (u8*)   alloc((size_t)NNODES * 256);      // 12.8 MB fp8 k
    bf16*  Wc       = (bf16*) alloc((size_t)NTOT * 128 * 2);    // 229 KB
    float* b896     = (float*)alloc(NTOT * 4);
    (void)ws_size;

    const int* srcArr = eidx;           // edge_index[0]
    const int* dstArr = eidx + NEDGES;  // edge_index[1]

    // CSR build (multi-block scan)
    int NB = (NNODES + 255) / 256;
    (void)hipMemsetAsync(deg, 0, NNODES * 4, stream);
    hist_kernel<<<(NEDGES + 255) / 256, 256, 0, stream>>>(dstArr, deg, NEDGES);
    scanA<<<NB, 256, 0, stream>>>(deg, cursor, blocksum, NNODES);
    scanB<<<1, 256, 0, stream>>>(blocksum, blockoff, NB, rowptr, NNODES);
    scanC<<<NB, 256, 0, stream>>>(deg, cursor, blockoff, rowptr, cursor, NNODES);
    scatter_kernel<<<(NEDGES + 255) / 256, 256, 0, stream>>>(srcArr, dstArr, cursor, csr2, NEDGES);

    // m-blocks: 196 blocks x 256 rows = 50176 >= 50000
    int NBY = (NNODES + 255) / 256;   // 196
    int fins[3] = {128, 64, 64};

    const void* hin = x;
    for (int l = 0; l < 3; l++) {
        int FIN = fins[l];
        pack_all<<<NTOT, FIN, 0, stream>>>(p[l].Wq, p[l].bq, p[l].Wk, p[l].bk,
                                           p[l].Wv, p[l].bv, p[l].We, p[l].Ws, p[l].bs,
                                           Wc, b896, FIN);
        if (l == 0) gemm_lds<float, 128><<<dim3(7, NBY), 256, 0, stream>>>((const float*)hin, Wc, b896, comb, vbuf, k8);
        else        gemm_lds<bf16,  64><<<dim3(7, NBY), 256, 0, stream>>>((const bf16*)hin,  Wc, b896, comb, vbuf, k8);
        node_fused<<<NNODES / 4, 256, 0, stream>>>(rowptr, csr2, eattr, (const u16*)comb,
            (const u16*)vbuf, k8, p[l].We, lng, lnb,
            (l == 2) ? nullptr : hbuf, (l == 2) ? (float*)d_out : nullptr);
        hin = hbuf;
    }
}